// Round 19
// baseline (230.069 us; speedup 1.0000x reference)
//
#include <hip/hip_runtime.h>
#include <hip/hip_bf16.h>

// Fused LayerNorm + QKV projection for B=4, S=2048, H=2048 (fp32 in/out).
//
// Round 19: r18's 4-phase merge (32 MFMA per barrier) with the vmcnt guards
// RESTORED to the r6-proven placement: end-of-phase, BEFORE the barrier.
// r18's failure (absmax 1.06): vmcnt is per-wave; a start-of-phase guard
// proves only the executing wave's gloads, but reads consume other waves'
// staged chunks -> needs [all waves prove] -> barrier -> [reads].
// Ledger (2 stage calls = 4 instrs/phase; steady 4->8->12->VM4->4):
//   prologue: 12 instrs, VM4 (proves buf0) BAR.
//   ph1-end VM4: drains prev-B1 + ph0-A1 -> buf1 proven before ph2 reads.
//   ph3-end VM4: drains ph1-B0 + ph2-A0 -> buf0@kt2 proven before ph0'.
//   i=15: ph1-end VM0 (stages skipped break the VM4 proof); ph3 nothing.

#define HD   2048            // hidden dim (K)
#define MTOT 8192            // B*S rows
#define NTOT 6144            // 3*H packed output cols
#define NIT  16              // iterations (2 K-tiles of BK=64 each)

typedef __attribute__((ext_vector_type(8))) _Float16 f16x8;   // 4 VGPR
typedef __attribute__((ext_vector_type(4))) _Float16 f16x4;
typedef __attribute__((ext_vector_type(4))) float f32x4;

// ---------------------------------------------------------------------------
// Kernel 1: LayerNorm -> fp16.  One block per row, 256 threads, 8 elems each.
// ---------------------------------------------------------------------------
__global__ __launch_bounds__(256) void ln_f16_kernel(
    const float* __restrict__ x, const float* __restrict__ gamma,
    const float* __restrict__ beta, _Float16* __restrict__ hi) {
  const int row = blockIdx.x;
  const float* xr = x + (size_t)row * HD;
  const int t = threadIdx.x;

  float4 v0 = reinterpret_cast<const float4*>(xr)[t * 2];
  float4 v1 = reinterpret_cast<const float4*>(xr)[t * 2 + 1];
  float xs[8] = {v0.x, v0.y, v0.z, v0.w, v1.x, v1.y, v1.z, v1.w};

  float s = 0.f, q = 0.f;
#pragma unroll
  for (int j = 0; j < 8; ++j) { s += xs[j]; q += xs[j] * xs[j]; }
#pragma unroll
  for (int off = 32; off; off >>= 1) {
    s += __shfl_down(s, off);
    q += __shfl_down(q, off);
  }
  __shared__ float red[8];
  const int wid = t >> 6, lane = t & 63;
  if (lane == 0) { red[wid] = s; red[4 + wid] = q; }
  __syncthreads();
  s = red[0] + red[1] + red[2] + red[3];
  q = red[4] + red[5] + red[6] + red[7];
  const float mu  = s * (1.f / HD);
  const float var = q * (1.f / HD) - mu * mu;
  const float rs  = rsqrtf(var + 1e-5f);

  float4 g0 = reinterpret_cast<const float4*>(gamma)[t * 2];
  float4 g1 = reinterpret_cast<const float4*>(gamma)[t * 2 + 1];
  float4 b0 = reinterpret_cast<const float4*>(beta)[t * 2];
  float4 b1 = reinterpret_cast<const float4*>(beta)[t * 2 + 1];
  float gs[8] = {g0.x, g0.y, g0.z, g0.w, g1.x, g1.y, g1.z, g1.w};
  float bs[8] = {b0.x, b0.y, b0.z, b0.w, b1.x, b1.y, b1.z, b1.w};

  f16x8 hv;
#pragma unroll
  for (int j = 0; j < 8; ++j) {
    float y = (xs[j] - mu) * rs * gs[j] + bs[j];
    hv[j] = (_Float16)y;
  }
  *reinterpret_cast<f16x8*>(&hi[(size_t)row * HD + t * 8]) = hv;
}

// ---------------------------------------------------------------------------
// Kernel 2: weights -> fp16 (q, k, v stacked).
// ---------------------------------------------------------------------------
__global__ __launch_bounds__(256) void w_f16_kernel(
    const float* __restrict__ qw, const float* __restrict__ kw,
    const float* __restrict__ vw, _Float16* __restrict__ hi) {
  const int m = blockIdx.y;
  const float* src = (m == 0) ? qw : (m == 1) ? kw : vw;
  const size_t base = (size_t)m * HD * HD;
  const int total4 = HD * HD / 4;
  for (int i = blockIdx.x * blockDim.x + threadIdx.x; i < total4;
       i += gridDim.x * blockDim.x) {
    float4 v = reinterpret_cast<const float4*>(src)[i];
    f16x4 hv;
    hv[0] = (_Float16)v.x; hv[1] = (_Float16)v.y;
    hv[2] = (_Float16)v.z; hv[3] = (_Float16)v.w;
    *reinterpret_cast<f16x4*>(&hi[base + (size_t)i * 4]) = hv;
  }
}

// ---------------------------------------------------------------------------
// Kernel 3: 256x256 4-phase fp16 GEMM, swizzled row-major LDS, coalesced
// staging.  out[m][n] = sum_k A[m][k] * W_p[n][k] + bias_p[n]
//
// LDS (128 KiB, f16): A bufs @ {0,16384}, B bufs @ {32768,49152}; each buf =
// row-major [256][64] f16.  Swizzle: slot s of row r holds k-chunk s^(r&7);
// staging loads global column ((t&7)^((t>>3)&7)) -> line-coalesced; read
// k-terms kk0/kk1 are per-thread constants (r15-r17 verified, 0 conflicts).
//
// Iteration i (K-tiles kt0=2i in buf0, kt1=2i+1 in buf1), 4 phases, each
// phase = [stage 2 calls][ds_reads][32 MFMA][LGKM0][vm guard?][BAR]:
//  ph0: stage buf1.A@kt1; read B0 both slices + A(0,mh0); MFMA mh0.
//  ph1: stage buf0.B@kt2; read A(0,mh1); MFMA mh1; VM4 (VM0 last iter).
//  ph2: stage buf0.A@kt2; read B1 + A(1,mh0); MFMA mh0.
//  ph3: stage buf1.B@kt3; read A(1,mh1); MFMA mh1; VM4 (skip last iter).
// RAW: ph1-end VM4 leaves only ph1's 4 in flight -> prev-ph3 B1 + ph0 A1
//   returned = buf1 complete; BARRIER; ph2 reads buf1 (cross-wave safe).
//   ph3-end VM4 leaves ph3's 4 -> ph1 B0 + ph2 A0 returned = buf0@kt2;
//   BARRIER; next-ph0 reads buf0.  Prologue VM4 proves buf0@kt0.
//   i=15: ph1's stage skipped -> proof-set = all outstanding -> VM0.
// WAR: each region's last read is LGKM0-fenced >=1 barrier before its
//   stage slot (B0 read ph0/staged ph1; A0 read ph1/staged ph2; B1 read
//   ph2/staged ph3; A1 read ph3/staged next-ph0).
// ---------------------------------------------------------------------------
__device__ __forceinline__ void gload16(const _Float16* g, _Float16* l) {
  __builtin_amdgcn_global_load_lds(
      (const __attribute__((address_space(1))) void*)g,
      (__attribute__((address_space(3))) void*)l, 16, 0, 0);
}

#define BAR()   asm volatile("s_barrier" ::: "memory")
#define LGKM0() asm volatile("s_waitcnt lgkmcnt(0)" ::: "memory")
#define VM4()   asm volatile("s_waitcnt vmcnt(4)" ::: "memory")
#define VM0()   asm volatile("s_waitcnt vmcnt(0)" ::: "memory")

// f16-offset reads: row*64 + swizzled k-term (KKV = kk0 or kk1).
#define LA(BUF, X, MH, KKV) \
  (*(const f16x8*)(lds + (BUF)*16384 + rA + (MH)*4096 + (X)*1024 + (KKV)))
#define LB(BUF, NR, KKV) \
  (*(const f16x8*)(lds + 32768 + (BUF)*16384 + rB + (NR)*1024 + (KKV)))

// Load ONE B k-slice (4 reads) into bfr[.][SL].
#define BHALF(BUF, SL, KKV) do { \
    bfr[0][SL]=LB(BUF,0,KKV); bfr[1][SL]=LB(BUF,1,KKV); \
    bfr[2][SL]=LB(BUF,2,KKV); bfr[3][SL]=LB(BUF,3,KKV); \
  } while (0)
#define ALD(T0, T1, T2, T3, BUF, MH, KKV) do { \
    T0 = LA(BUF, 0, MH, KKV); T1 = LA(BUF, 1, MH, KKV); \
    T2 = LA(BUF, 2, MH, KKV); T3 = LA(BUF, 3, MH, KKV); \
  } while (0)

#define MF(A, B, C) __builtin_amdgcn_mfma_f32_16x16x32_f16(A, B, C, 0, 0, 0)
#define MFMAS(A0, A1, A2, A3, MH, KS) do { \
    acc[(MH)*4+0][0]=MF(A0,bfr[0][KS],acc[(MH)*4+0][0]); \
    acc[(MH)*4+0][1]=MF(A0,bfr[1][KS],acc[(MH)*4+0][1]); \
    acc[(MH)*4+0][2]=MF(A0,bfr[2][KS],acc[(MH)*4+0][2]); \
    acc[(MH)*4+0][3]=MF(A0,bfr[3][KS],acc[(MH)*4+0][3]); \
    acc[(MH)*4+1][0]=MF(A1,bfr[0][KS],acc[(MH)*4+1][0]); \
    acc[(MH)*4+1][1]=MF(A1,bfr[1][KS],acc[(MH)*4+1][1]); \
    acc[(MH)*4+1][2]=MF(A1,bfr[2][KS],acc[(MH)*4+1][2]); \
    acc[(MH)*4+1][3]=MF(A1,bfr[3][KS],acc[(MH)*4+1][3]); \
    acc[(MH)*4+2][0]=MF(A2,bfr[0][KS],acc[(MH)*4+2][0]); \
    acc[(MH)*4+2][1]=MF(A2,bfr[1][KS],acc[(MH)*4+2][1]); \
    acc[(MH)*4+2][2]=MF(A2,bfr[2][KS],acc[(MH)*4+2][2]); \
    acc[(MH)*4+2][3]=MF(A2,bfr[3][KS],acc[(MH)*4+2][3]); \
    acc[(MH)*4+3][0]=MF(A3,bfr[0][KS],acc[(MH)*4+3][0]); \
    acc[(MH)*4+3][1]=MF(A3,bfr[1][KS],acc[(MH)*4+3][1]); \
    acc[(MH)*4+3][2]=MF(A3,bfr[2][KS],acc[(MH)*4+3][2]); \
    acc[(MH)*4+3][3]=MF(A3,bfr[3][KS],acc[(MH)*4+3][3]); \
  } while (0)

__global__ __launch_bounds__(512, 2) void qkv_gemm_kernel(
    const _Float16* __restrict__ Ah, const _Float16* __restrict__ Wh,
    const float* __restrict__ qb, const float* __restrict__ kb,
    const float* __restrict__ vb, float* __restrict__ out) {
  extern __shared__ _Float16 lds[];   // 131072 B

  const int t    = threadIdx.x;
  const int lane = t & 63;
  const int wid  = t >> 6;            // 0..7
  const int wm   = wid >> 2;          // 0..1 (M)
  const int wn   = wid & 3;           // 0..3 (N)
  const int fr   = lane & 15;
  const int fq   = lane >> 4;

  const int n0  = blockIdx.x * 256;
  const int m0  = blockIdx.y * 256;
  const int p   = n0 >> 11;
  const int ln0 = n0 & (HD - 1);
  const _Float16* Ag  = Ah + (size_t)m0 * HD;
  const _Float16* Bgp = Wh + (size_t)p * HD * HD + (size_t)ln0 * HD;
  const float* bias = (p == 0) ? qb : (p == 1) ? kb : vb;

  // Staging invariants (coalesced + inverse-swizzled source).
  const int srow = t >> 3;                              // 0..63
  const int scol = ((t & 7) ^ (srow & 7)) * 8;          // f16 offset in row
  // Fragment-read invariants.
  const int rA  = (wm * 128 + fr) * 64;
  const int rB  = (wn * 64 + fr) * 64;
  const int kk0 = ((fq) ^ (fr & 7)) * 8;
  const int kk1 = ((4 + fq) ^ (fr & 7)) * 8;

  auto stA = [&](int buf, int hf, int kt) {
    const _Float16* g = Ag + (size_t)(hf * 64 + srow) * HD + kt * 64 + scol;
    _Float16* l = lds + buf * 16384 + (hf * 512 + t) * 8;
    gload16(g, l);
    gload16(g + (size_t)128 * HD, l + 8192);
  };
  auto stB = [&](int buf, int hf, int kt) {
    const _Float16* g = Bgp + (size_t)(hf * 64 + srow) * HD + kt * 64 + scol;
    _Float16* l = lds + 32768 + buf * 16384 + (hf * 512 + t) * 8;
    gload16(g, l);
    gload16(g + (size_t)128 * HD, l + 8192);
  };

  f32x4 acc[8][4] = {};

  // Fragment registers: B rotating set (32 VGPR) + A sets x/y (16+16).
  f16x8 bfr[4][2];
  f16x8 x0, x1, x2, x3;
  f16x8 y0, y1, y2, y3;

  // Prologue: buf0 <- K-tile 0 (A+B, 4 calls), buf1 <- K-tile 1 B (2 calls).
  // VM4 leaves buf1-B's 4 in flight -> buf0 fully proven; then barrier.
  stB(0, 0, 0); stB(0, 1, 0); stA(0, 0, 0); stA(0, 1, 0);
  stB(1, 0, 1); stB(1, 1, 1);
  VM4();
  BAR();

#pragma unroll 1
  for (int i = 0; i < NIT; ++i) {
    const bool nl = (i < NIT - 1);
    const int kt1 = 2 * i + 1, kt2 = 2 * i + 2, kt3 = 2 * i + 3;

    // ---- ph0: buf0 mh0 (32 MFMA); stage buf1.A @ kt1 ----
    stA(1, 0, kt1); stA(1, 1, kt1);
    BHALF(0, 0, kk0);
    ALD(x0, x1, x2, x3, 0, 0, kk0);
    BHALF(0, 1, kk1);
    ALD(y0, y1, y2, y3, 0, 0, kk1);
    __builtin_amdgcn_s_setprio(1);
    MFMAS(x0, x1, x2, x3, 0, 0);
    MFMAS(y0, y1, y2, y3, 0, 1);
    __builtin_amdgcn_s_setprio(0);
    LGKM0(); BAR();

    // ---- ph1: buf0 mh1; stage buf0.B @ kt2; guard buf1 ----
    if (nl) { stB(0, 0, kt2); stB(0, 1, kt2); }
    ALD(x0, x1, x2, x3, 0, 1, kk0);
    ALD(y0, y1, y2, y3, 0, 1, kk1);
    __builtin_amdgcn_s_setprio(1);
    MFMAS(x0, x1, x2, x3, 1, 0);
    MFMAS(y0, y1, y2, y3, 1, 1);
    __builtin_amdgcn_s_setprio(0);
    LGKM0();
    if (nl) { VM4(); } else { VM0(); }   // buf1@kt1 proven (all waves), then BAR
    BAR();

    // ---- ph2: buf1 mh0; stage buf0.A @ kt2 ----
    if (nl) { stA(0, 0, kt2); stA(0, 1, kt2); }
    BHALF(1, 0, kk0);
    ALD(x0, x1, x2, x3, 1, 0, kk0);
    BHALF(1, 1, kk1);
    ALD(y0, y1, y2, y3, 1, 0, kk1);
    __builtin_amdgcn_s_setprio(1);
    MFMAS(x0, x1, x2, x3, 0, 0);
    MFMAS(y0, y1, y2, y3, 0, 1);
    __builtin_amdgcn_s_setprio(0);
    LGKM0(); BAR();

    // ---- ph3: buf1 mh1; stage buf1.B @ kt3; guard buf0@kt2 ----
    if (nl) { stB(1, 0, kt3); stB(1, 1, kt3); }
    ALD(x0, x1, x2, x3, 1, 1, kk0);
    ALD(y0, y1, y2, y3, 1, 1, kk1);
    __builtin_amdgcn_s_setprio(1);
    MFMAS(x0, x1, x2, x3, 1, 0);
    MFMAS(y0, y1, y2, y3, 1, 1);
    __builtin_amdgcn_s_setprio(0);
    LGKM0();
    if (nl) { VM4(); }                   // buf0@kt2 proven, then BAR
    BAR();
  }

  // Epilogue: C/D layout col = lane&15, row = (lane>>4)*4 + reg.
  float bv[4];
#pragma unroll
  for (int nr = 0; nr < 4; ++nr)
    bv[nr] = bias[(ln0 + wn * 64 + nr * 16 + fr)];
#pragma unroll
  for (int mr = 0; mr < 8; ++mr) {
    const int r0 = m0 + wm * 128 + mr * 16 + fq * 4;
#pragma unroll
    for (int nr = 0; nr < 4; ++nr) {
      const int cg = n0 + wn * 64 + nr * 16 + fr;
      f32x4 v = acc[mr][nr];
#pragma unroll
      for (int r = 0; r < 4; ++r)
        out[(size_t)(r0 + r) * NTOT + cg] = v[r] + bv[nr];
    }
  }
}

// ---------------------------------------------------------------------------
extern "C" void kernel_launch(void* const* d_in, const int* in_sizes, int n_in,
                              void* d_out, int out_size, void* d_ws,
                              size_t ws_size, hipStream_t stream) {
  const float* x     = (const float*)d_in[0];
  const float* gamma = (const float*)d_in[1];
  const float* beta  = (const float*)d_in[2];
  const float* qw    = (const float*)d_in[3];
  const float* qb    = (const float*)d_in[4];
  const float* kw    = (const float*)d_in[5];
  const float* kbia  = (const float*)d_in[6];
  const float* vw    = (const float*)d_in[7];
  const float* vb    = (const float*)d_in[8];
  float* out = (float*)d_out;

  // Workspace: [0, 32M) normed fp16 [8192][2048]; [32M, 56M) W fp16 [3][2048][2048]
  char* ws = (char*)d_ws;
  _Float16* Ahp = (_Float16*)(ws);
  _Float16* Whp = (_Float16*)(ws + (size_t)MTOT * HD * 2);

  (void)hipFuncSetAttribute((const void*)qkv_gemm_kernel,
                            hipFuncAttributeMaxDynamicSharedMemorySize, 131072);

  ln_f16_kernel<<<MTOT, 256, 0, stream>>>(x, gamma, beta, Ahp);
  w_f16_kernel<<<dim3(1024, 3), 256, 0, stream>>>(qw, kw, vw, Whp);
  qkv_gemm_kernel<<<dim3(NTOT / 256, MTOT / 256), 512, 131072, stream>>>(
      Ahp, Whp, qb, kbia, vb, out);
}

// Round 20
// 228.732 us; speedup vs baseline: 1.0058x; 1.0058x over previous
//
#include <hip/hip_runtime.h>
#include <hip/hip_bf16.h>

// Fused LayerNorm + QKV projection for B=4, S=2048, H=2048 (fp32 in/out).
//
// Round 20: r17 (full A+B lookahead, 196us, MfmaUtil 47%) with the phase-end
// lgkmcnt(0) RELAXED to counted lgkmcnt(4/8). r16/r17/r19 proved the plateau
// is the blanket LGKM0: it forces the CU's LDS queue to drain inside every
// phase, so lookahead reads never overlap the next phase's MFMAs (phase =
// LDS 578 + MFMA 621 serialized). The counted fence keeps only the WAR-
// critical reads (those targeting a region staged in the NEXT phase) and
// lets the rest (FIFO-last A-reads / cross-buffer reads) drain under the
// next phase's MFMA window. Per-phase WAR proof in comments below.
// Stage slots + VM6/VM0 vmcnt ledger + swizzle = r17 exactly (passed).

#define HD   2048            // hidden dim (K)
#define MTOT 8192            // B*S rows
#define NTOT 6144            // 3*H packed output cols
#define NIT  16              // iterations (2 K-tiles of BK=64 each)

typedef __attribute__((ext_vector_type(8))) _Float16 f16x8;   // 4 VGPR
typedef __attribute__((ext_vector_type(4))) _Float16 f16x4;
typedef __attribute__((ext_vector_type(4))) float f32x4;

// ---------------------------------------------------------------------------
// Kernel 1: LayerNorm -> fp16.  One block per row, 256 threads, 8 elems each.
// ---------------------------------------------------------------------------
__global__ __launch_bounds__(256) void ln_f16_kernel(
    const float* __restrict__ x, const float* __restrict__ gamma,
    const float* __restrict__ beta, _Float16* __restrict__ hi) {
  const int row = blockIdx.x;
  const float* xr = x + (size_t)row * HD;
  const int t = threadIdx.x;

  float4 v0 = reinterpret_cast<const float4*>(xr)[t * 2];
  float4 v1 = reinterpret_cast<const float4*>(xr)[t * 2 + 1];
  float xs[8] = {v0.x, v0.y, v0.z, v0.w, v1.x, v1.y, v1.z, v1.w};

  float s = 0.f, q = 0.f;
#pragma unroll
  for (int j = 0; j < 8; ++j) { s += xs[j]; q += xs[j] * xs[j]; }
#pragma unroll
  for (int off = 32; off; off >>= 1) {
    s += __shfl_down(s, off);
    q += __shfl_down(q, off);
  }
  __shared__ float red[8];
  const int wid = t >> 6, lane = t & 63;
  if (lane == 0) { red[wid] = s; red[4 + wid] = q; }
  __syncthreads();
  s = red[0] + red[1] + red[2] + red[3];
  q = red[4] + red[5] + red[6] + red[7];
  const float mu  = s * (1.f / HD);
  const float var = q * (1.f / HD) - mu * mu;
  const float rs  = rsqrtf(var + 1e-5f);

  float4 g0 = reinterpret_cast<const float4*>(gamma)[t * 2];
  float4 g1 = reinterpret_cast<const float4*>(gamma)[t * 2 + 1];
  float4 b0 = reinterpret_cast<const float4*>(beta)[t * 2];
  float4 b1 = reinterpret_cast<const float4*>(beta)[t * 2 + 1];
  float gs[8] = {g0.x, g0.y, g0.z, g0.w, g1.x, g1.y, g1.z, g1.w};
  float bs[8] = {b0.x, b0.y, b0.z, b0.w, b1.x, b1.y, b1.z, b1.w};

  f16x8 hv;
#pragma unroll
  for (int j = 0; j < 8; ++j) {
    float y = (xs[j] - mu) * rs * gs[j] + bs[j];
    hv[j] = (_Float16)y;
  }
  *reinterpret_cast<f16x8*>(&hi[(size_t)row * HD + t * 8]) = hv;
}

// ---------------------------------------------------------------------------
// Kernel 2: weights -> fp16 (q, k, v stacked).
// ---------------------------------------------------------------------------
__global__ __launch_bounds__(256) void w_f16_kernel(
    const float* __restrict__ qw, const float* __restrict__ kw,
    const float* __restrict__ vw, _Float16* __restrict__ hi) {
  const int m = blockIdx.y;
  const float* src = (m == 0) ? qw : (m == 1) ? kw : vw;
  const size_t base = (size_t)m * HD * HD;
  const int total4 = HD * HD / 4;
  for (int i = blockIdx.x * blockDim.x + threadIdx.x; i < total4;
       i += gridDim.x * blockDim.x) {
    float4 v = reinterpret_cast<const float4*>(src)[i];
    f16x4 hv;
    hv[0] = (_Float16)v.x; hv[1] = (_Float16)v.y;
    hv[2] = (_Float16)v.z; hv[3] = (_Float16)v.w;
    *reinterpret_cast<f16x4*>(&hi[base + (size_t)i * 4]) = hv;
  }
}

// ---------------------------------------------------------------------------
// Kernel 3: 256x256 8-phase fp16 GEMM, swizzled row-major LDS, coalesced
// staging, full A+B lookahead, COUNTED phase-end lgkm fences.
// out[m][n] = sum_k A[m][k] * W_p[n][k] + bias_p[n]
//
// LDS (128 KiB, f16): A bufs @ {0,16384}, B bufs @ {32768,49152}; each buf =
// row-major [256][64] f16.  Swizzle: slot s of row r holds k-chunk s^(r&7);
// staging loads global column ((t&7)^((t>>3)&7)) -> line-coalesced; read
// k-terms kk0/kk1 per-thread constants (r15-r19 verified, 0 conflicts).
//
// Region map: A-half h0 = rows 0-63 & 128-191; h1 = 64-127 & 192-255.
//   A mh0 reads live in h0; mh1 reads in h1.  B stage halves likewise.
// Phase-end fence derivation (pending = this phase's lookahead reads, FIFO;
// next phase's stage region in [];  fence keeps only conflicting reads):
//  P0-end: pending B0-ks1 + A0mh0-ks1; [P1 stages B0-h0 all-k] -> fence B
//          (issued first) -> lgkmcnt(4) leaves only A pending.  SAFE.
//  P1-end: pending A0mh1-ks0 (4); [P2 stages B0-h1] disjoint -> lgkmcnt(4).
//  P2-end: pending A0mh1-ks1; [P3 stages A0-h0] mh1 is h1, disjoint -> (4).
//  P3-end: pending B1-ks0 + A1mh0-ks0 (8, all buf1); [P4 stages A0-h1]
//          disjoint buf -> lgkmcnt(8).
//  P4-end: pending B1-ks1 + A1mh0-ks1; [P5 stages B1-h0] -> fence B ->
//          lgkmcnt(4) (A issued last).
//  P5-end: pending A1mh1-ks0; [P6 stages B1-h1] disjoint -> lgkmcnt(4).
//  P6-end: pending A1mh1-ks1; [P7 stages A1-h0] mh1 in h1 -> lgkmcnt(4).
//  P7-end: pending B0'-ks0 + A0'mh0-ks0 (buf0); [next-P0 stages A1-h1]
//          disjoint buf -> lgkmcnt(8).
// RAW across barriers: consumers are C++ register deps; compiler emits
// per-use lgkm waits (rule #18 does not apply to non-asm reads).
// Stage slots + VM6@P3 / VM6@P7 / VM0-tail vmcnt ledger = r6..r17 (passed).
// ---------------------------------------------------------------------------
__device__ __forceinline__ void gload16(const _Float16* g, _Float16* l) {
  __builtin_amdgcn_global_load_lds(
      (const __attribute__((address_space(1))) void*)g,
      (__attribute__((address_space(3))) void*)l, 16, 0, 0);
}

#define BAR()   asm volatile("s_barrier" ::: "memory")
#define LGKM4() asm volatile("s_waitcnt lgkmcnt(4)" ::: "memory")
#define LGKM8() asm volatile("s_waitcnt lgkmcnt(8)" ::: "memory")
#define VM6()   asm volatile("s_waitcnt vmcnt(6)" ::: "memory")
#define VM0()   asm volatile("s_waitcnt vmcnt(0)" ::: "memory")

// f16-offset reads: row*64 + swizzled k-term (KKV = kk0 or kk1).
#define LA(BUF, X, MH, KKV) \
  (*(const f16x8*)(lds + (BUF)*16384 + rA + (MH)*4096 + (X)*1024 + (KKV)))
#define LB(BUF, NR, KKV) \
  (*(const f16x8*)(lds + 32768 + (BUF)*16384 + rB + (NR)*1024 + (KKV)))

// Load ONE B k-slice (4 reads) into bfr[.][SL].
#define BHALF(BUF, SL, KKV) do { \
    bfr[0][SL]=LB(BUF,0,KKV); bfr[1][SL]=LB(BUF,1,KKV); \
    bfr[2][SL]=LB(BUF,2,KKV); bfr[3][SL]=LB(BUF,3,KKV); \
  } while (0)
#define ALD(T0, T1, T2, T3, BUF, MH, KKV) do { \
    T0 = LA(BUF, 0, MH, KKV); T1 = LA(BUF, 1, MH, KKV); \
    T2 = LA(BUF, 2, MH, KKV); T3 = LA(BUF, 3, MH, KKV); \
  } while (0)

#define MF(A, B, C) __builtin_amdgcn_mfma_f32_16x16x32_f16(A, B, C, 0, 0, 0)
#define MFMAS(A0, A1, A2, A3, MH, KS) do { \
    __builtin_amdgcn_s_setprio(1); \
    acc[(MH)*4+0][0]=MF(A0,bfr[0][KS],acc[(MH)*4+0][0]); \
    acc[(MH)*4+0][1]=MF(A0,bfr[1][KS],acc[(MH)*4+0][1]); \
    acc[(MH)*4+0][2]=MF(A0,bfr[2][KS],acc[(MH)*4+0][2]); \
    acc[(MH)*4+0][3]=MF(A0,bfr[3][KS],acc[(MH)*4+0][3]); \
    acc[(MH)*4+1][0]=MF(A1,bfr[0][KS],acc[(MH)*4+1][0]); \
    acc[(MH)*4+1][1]=MF(A1,bfr[1][KS],acc[(MH)*4+1][1]); \
    acc[(MH)*4+1][2]=MF(A1,bfr[2][KS],acc[(MH)*4+1][2]); \
    acc[(MH)*4+1][3]=MF(A1,bfr[3][KS],acc[(MH)*4+1][3]); \
    acc[(MH)*4+2][0]=MF(A2,bfr[0][KS],acc[(MH)*4+2][0]); \
    acc[(MH)*4+2][1]=MF(A2,bfr[1][KS],acc[(MH)*4+2][1]); \
    acc[(MH)*4+2][2]=MF(A2,bfr[2][KS],acc[(MH)*4+2][2]); \
    acc[(MH)*4+2][3]=MF(A2,bfr[3][KS],acc[(MH)*4+2][3]); \
    acc[(MH)*4+3][0]=MF(A3,bfr[0][KS],acc[(MH)*4+3][0]); \
    acc[(MH)*4+3][1]=MF(A3,bfr[1][KS],acc[(MH)*4+3][1]); \
    acc[(MH)*4+3][2]=MF(A3,bfr[2][KS],acc[(MH)*4+3][2]); \
    acc[(MH)*4+3][3]=MF(A3,bfr[3][KS],acc[(MH)*4+3][3]); \
    __builtin_amdgcn_s_setprio(0); \
  } while (0)

__global__ __launch_bounds__(512, 2) void qkv_gemm_kernel(
    const _Float16* __restrict__ Ah, const _Float16* __restrict__ Wh,
    const float* __restrict__ qb, const float* __restrict__ kb,
    const float* __restrict__ vb, float* __restrict__ out) {
  extern __shared__ _Float16 lds[];   // 131072 B

  const int t    = threadIdx.x;
  const int lane = t & 63;
  const int wid  = t >> 6;            // 0..7
  const int wm   = wid >> 2;          // 0..1 (M)
  const int wn   = wid & 3;           // 0..3 (N)
  const int fr   = lane & 15;
  const int fq   = lane >> 4;

  const int n0  = blockIdx.x * 256;
  const int m0  = blockIdx.y * 256;
  const int p   = n0 >> 11;
  const int ln0 = n0 & (HD - 1);
  const _Float16* Ag  = Ah + (size_t)m0 * HD;
  const _Float16* Bgp = Wh + (size_t)p * HD * HD + (size_t)ln0 * HD;
  const float* bias = (p == 0) ? qb : (p == 1) ? kb : vb;

  // Staging invariants (coalesced + inverse-swizzled source).
  const int srow = t >> 3;                              // 0..63
  const int scol = ((t & 7) ^ (srow & 7)) * 8;          // f16 offset in row
  // Fragment-read invariants.
  const int rA  = (wm * 128 + fr) * 64;
  const int rB  = (wn * 64 + fr) * 64;
  const int kk0 = ((fq) ^ (fr & 7)) * 8;
  const int kk1 = ((4 + fq) ^ (fr & 7)) * 8;

  auto stA = [&](int buf, int hf, int kt) {
    const _Float16* g = Ag + (size_t)(hf * 64 + srow) * HD + kt * 64 + scol;
    _Float16* l = lds + buf * 16384 + (hf * 512 + t) * 8;
    gload16(g, l);
    gload16(g + (size_t)128 * HD, l + 8192);
  };
  auto stB = [&](int buf, int hf, int kt) {
    const _Float16* g = Bgp + (size_t)(hf * 64 + srow) * HD + kt * 64 + scol;
    _Float16* l = lds + 32768 + buf * 16384 + (hf * 512 + t) * 8;
    gload16(g, l);
    gload16(g + (size_t)128 * HD, l + 8192);
  };

  f32x4 acc[8][4] = {};

  // Fragment registers: B rotating set (32 VGPR) + A double sets x/y (16+16).
  f16x8 bfr[4][2];
  f16x8 x0, x1, x2, x3;
  f16x8 y0, y1, y2, y3;

  // Prologue: buf0 <- K-tile 0 (4 halves), buf1 <- K-tile 1 (3 halves).
  // vmcnt(6) = 3 calls in flight -> buf0 fully landed.
  stB(0, 0, 0); stB(0, 1, 0); stA(0, 0, 0); stA(0, 1, 0);
  stB(1, 0, 1); stB(1, 1, 1); stA(1, 0, 1);
  VM6();
  BAR();
  // Seed P0's inputs (buf0 proven): B0-ks0 and A(mh0,ks0).
  BHALF(0, 0, kk0);
  ALD(x0, x1, x2, x3, 0, 0, kk0);

#pragma unroll 1
  for (int i = 0; i < NIT; ++i) {
    const bool nl = (i < NIT - 1);
    const int kt1 = 2 * i + 1, kt2 = 2 * i + 2, kt3 = 2 * i + 3;

    // ---- P0: MFMA buf0(mh0,ks0); load B0-ks1 + y<-(0,mh0,ks1) ----
    stA(1, 1, kt1);
    BHALF(0, 1, kk1);
    ALD(y0, y1, y2, y3, 0, 0, kk1);
    MFMAS(x0, x1, x2, x3, 0, 0);
    LGKM4(); BAR();                          // fence B0-ks1; A may pend

    // ---- P1: MFMA buf0(mh0,ks1); x<-(0,mh1,ks0) ----
    if (nl) stB(0, 0, kt2);
    ALD(x0, x1, x2, x3, 0, 1, kk0);
    MFMAS(y0, y1, y2, y3, 0, 1);
    LGKM4(); BAR();                          // pending A vs B-stage: disjoint

    // ---- P2: MFMA buf0(mh1,ks0); y<-(0,mh1,ks1) ----
    if (nl) stB(0, 1, kt2);
    ALD(y0, y1, y2, y3, 0, 1, kk1);
    MFMAS(x0, x1, x2, x3, 1, 0);
    LGKM4(); BAR();                          // pending A-h1 vs A-h0 stage

    // ---- P3: MFMA buf0(mh1,ks1); guard buf1; load B1-ks0 + x<-(1,mh0,ks0)
    if (nl) { stA(0, 0, kt2); VM6(); } else { VM0(); }
    BHALF(1, 0, kk0);
    ALD(x0, x1, x2, x3, 1, 0, kk0);
    MFMAS(y0, y1, y2, y3, 1, 1);
    LGKM8(); BAR();                          // pending buf1 vs buf0 stage

    // ---- P4: MFMA buf1(mh0,ks0); load B1-ks1 + y<-(1,mh0,ks1) ----
    if (nl) stA(0, 1, kt2);
    BHALF(1, 1, kk1);
    ALD(y0, y1, y2, y3, 1, 0, kk1);
    MFMAS(x0, x1, x2, x3, 0, 0);
    LGKM4(); BAR();                          // fence B1-ks1; A may pend

    // ---- P5: MFMA buf1(mh0,ks1); x<-(1,mh1,ks0) ----
    if (nl) stB(1, 0, kt3);
    ALD(x0, x1, x2, x3, 1, 1, kk0);
    MFMAS(y0, y1, y2, y3, 0, 1);
    LGKM4(); BAR();

    // ---- P6: MFMA buf1(mh1,ks0); y<-(1,mh1,ks1) ----
    if (nl) stB(1, 1, kt3);
    ALD(y0, y1, y2, y3, 1, 1, kk1);
    MFMAS(x0, x1, x2, x3, 1, 0);
    LGKM4(); BAR();                          // pending A-h1 vs A-h0 stage

    // ---- P7: MFMA buf1(mh1,ks1); guard buf0@kt2; load B0'-ks0 + seed x --
    if (nl) {
      stA(1, 0, kt3);
      VM6();
      BHALF(0, 0, kk0);
      ALD(x0, x1, x2, x3, 0, 0, kk0);
    }
    MFMAS(y0, y1, y2, y3, 1, 1);
    LGKM8(); BAR();                          // pending buf0 vs buf1-h1 stage
  }

  // Epilogue: C/D layout col = lane&15, row = (lane>>4)*4 + reg.
  float bv[4];
#pragma unroll
  for (int nr = 0; nr < 4; ++nr)
    bv[nr] = bias[(ln0 + wn * 64 + nr * 16 + fr)];
#pragma unroll
  for (int mr = 0; mr < 8; ++mr) {
    const int r0 = m0 + wm * 128 + mr * 16 + fq * 4;
#pragma unroll
    for (int nr = 0; nr < 4; ++nr) {
      const int cg = n0 + wn * 64 + nr * 16 + fr;
      f32x4 v = acc[mr][nr];
#pragma unroll
      for (int r = 0; r < 4; ++r)
        out[(size_t)(r0 + r) * NTOT + cg] = v[r] + bv[nr];
    }
  }
}

// ---------------------------------------------------------------------------
extern "C" void kernel_launch(void* const* d_in, const int* in_sizes, int n_in,
                              void* d_out, int out_size, void* d_ws,
                              size_t ws_size, hipStream_t stream) {
  const float* x     = (const float*)d_in[0];
  const float* gamma = (const float*)d_in[1];
  const float* beta  = (const float*)d_in[2];
  const float* qw    = (const float*)d_in[3];
  const float* qb    = (const float*)d_in[4];
  const float* kw    = (const float*)d_in[5];
  const float* kbia  = (const float*)d_in[6];
  const float* vw    = (const float*)d_in[7];
  const float* vb    = (const float*)d_in[8];
  float* out = (float*)d_out;

  // Workspace: [0, 32M) normed fp16 [8192][2048]; [32M, 56M) W fp16 [3][2048][2048]
  char* ws = (char*)d_ws;
  _Float16* Ahp = (_Float16*)(ws);
  _Float16* Whp = (_Float16*)(ws + (size_t)MTOT * HD * 2);

  (void)hipFuncSetAttribute((const void*)qkv_gemm_kernel,
                            hipFuncAttributeMaxDynamicSharedMemorySize, 131072);

  ln_f16_kernel<<<MTOT, 256, 0, stream>>>(x, gamma, beta, Ahp);
  w_f16_kernel<<<dim3(1024, 3), 256, 0, stream>>>(qw, kw, vw, Whp);
  qkv_gemm_kernel<<<dim3(NTOT / 256, MTOT / 256), 512, 131072, stream>>>(
      Ahp, Whp, qb, kbia, vb, out);
}

// Round 21
// 224.805 us; speedup vs baseline: 1.0234x; 1.0175x over previous
//
#include <hip/hip_runtime.h>
#include <hip/hip_bf16.h>

// Fused LayerNorm + QKV projection for B=4, S=2048, H=2048 (fp32 in/out).
//
// Round 21: r20's GEMM unchanged (196us - r15..r20 proved the K-loop sits on
// the LDS-bandwidth wall: 112 KB/phase/CU at ~90 B/cyc = the measured 1220
// cyc/phase; schedule variants are all neutral). This round merges the two
// prologue kernels (LN 96 MB + W-convert 72 MB, previously sequential) into
// ONE launch so their memory streams overlap and one launch gap disappears:
// ~33us -> ~27us of prologue.

#define HD   2048            // hidden dim (K)
#define MTOT 8192            // B*S rows
#define NTOT 6144            // 3*H packed output cols
#define NIT  16              // iterations (2 K-tiles of BK=64 each)

typedef __attribute__((ext_vector_type(8))) _Float16 f16x8;   // 4 VGPR
typedef __attribute__((ext_vector_type(4))) _Float16 f16x4;
typedef __attribute__((ext_vector_type(4))) float f32x4;

// ---------------------------------------------------------------------------
// Kernel 1 (merged prologue): blocks [0, MTOT) do LayerNorm->fp16 (one row
// each); blocks [MTOT, MTOT+3072) convert the three weight matrices to fp16
// (grid-stride over HD*HD/4 float4 chunks each). Branch is block-uniform.
// ---------------------------------------------------------------------------
__global__ __launch_bounds__(256) void prep_kernel(
    const float* __restrict__ x, const float* __restrict__ gamma,
    const float* __restrict__ beta, const float* __restrict__ qw,
    const float* __restrict__ kw, const float* __restrict__ vw,
    _Float16* __restrict__ Ah, _Float16* __restrict__ Wh) {
  const int t = threadIdx.x;

  if (blockIdx.x < MTOT) {
    // ---- LayerNorm branch: one row per block, 256 threads x 8 elems ----
    const int row = blockIdx.x;
    const float* xr = x + (size_t)row * HD;

    float4 v0 = reinterpret_cast<const float4*>(xr)[t * 2];
    float4 v1 = reinterpret_cast<const float4*>(xr)[t * 2 + 1];
    float xs[8] = {v0.x, v0.y, v0.z, v0.w, v1.x, v1.y, v1.z, v1.w};

    float s = 0.f, q = 0.f;
#pragma unroll
    for (int j = 0; j < 8; ++j) { s += xs[j]; q += xs[j] * xs[j]; }
#pragma unroll
    for (int off = 32; off; off >>= 1) {
      s += __shfl_down(s, off);
      q += __shfl_down(q, off);
    }
    __shared__ float red[8];
    const int wid = t >> 6, lane = t & 63;
    if (lane == 0) { red[wid] = s; red[4 + wid] = q; }
    __syncthreads();
    s = red[0] + red[1] + red[2] + red[3];
    q = red[4] + red[5] + red[6] + red[7];
    const float mu  = s * (1.f / HD);
    const float var = q * (1.f / HD) - mu * mu;
    const float rs  = rsqrtf(var + 1e-5f);

    float4 g0 = reinterpret_cast<const float4*>(gamma)[t * 2];
    float4 g1 = reinterpret_cast<const float4*>(gamma)[t * 2 + 1];
    float4 b0 = reinterpret_cast<const float4*>(beta)[t * 2];
    float4 b1 = reinterpret_cast<const float4*>(beta)[t * 2 + 1];
    float gs[8] = {g0.x, g0.y, g0.z, g0.w, g1.x, g1.y, g1.z, g1.w};
    float bs[8] = {b0.x, b0.y, b0.z, b0.w, b1.x, b1.y, b1.z, b1.w};

    f16x8 hv;
#pragma unroll
    for (int j = 0; j < 8; ++j) {
      float y = (xs[j] - mu) * rs * gs[j] + bs[j];
      hv[j] = (_Float16)y;
    }
    *reinterpret_cast<f16x8*>(&Ah[(size_t)row * HD + t * 8]) = hv;
  } else {
    // ---- Weight-convert branch: 3072 blocks, 1024 per matrix ----
    const int wb = blockIdx.x - MTOT;        // 0..3071
    const int m  = wb / 1024;                // which matrix
    const int b0 = wb % 1024;
    const float* src = (m == 0) ? qw : (m == 1) ? kw : vw;
    const size_t base = (size_t)m * HD * HD;
    const int total4 = HD * HD / 4;
    for (int i = b0 * 256 + t; i < total4; i += 1024 * 256) {
      float4 v = reinterpret_cast<const float4*>(src)[i];
      f16x4 hv;
      hv[0] = (_Float16)v.x; hv[1] = (_Float16)v.y;
      hv[2] = (_Float16)v.z; hv[3] = (_Float16)v.w;
      *reinterpret_cast<f16x4*>(&Wh[base + (size_t)i * 4]) = hv;
    }
  }
}

// ---------------------------------------------------------------------------
// Kernel 2: 256x256 8-phase fp16 GEMM (= round 20, best measured: 196us).
// Swizzled row-major LDS, coalesced staging, full A+B lookahead, counted
// phase-end lgkm fences.  out[m][n] = sum_k A[m][k]*W_p[n][k] + bias_p[n]
//
// LDS (128 KiB, f16): A bufs @ {0,16384}, B bufs @ {32768,49152}; each buf =
// row-major [256][64] f16.  Swizzle: slot s of row r holds k-chunk s^(r&7);
// staging loads global column ((t&7)^((t>>3)&7)) -> line-coalesced; read
// k-terms kk0/kk1 per-thread constants (r15-r20 verified, 0 conflicts).
// Stage slots + VM6@P3 / VM6@P7 / VM0-tail vmcnt ledger = r6..r20 (passed).
// Phase-end counted lgkm fences per the r20 WAR derivation (passed).
// ---------------------------------------------------------------------------
__device__ __forceinline__ void gload16(const _Float16* g, _Float16* l) {
  __builtin_amdgcn_global_load_lds(
      (const __attribute__((address_space(1))) void*)g,
      (__attribute__((address_space(3))) void*)l, 16, 0, 0);
}

#define BAR()   asm volatile("s_barrier" ::: "memory")
#define LGKM4() asm volatile("s_waitcnt lgkmcnt(4)" ::: "memory")
#define LGKM8() asm volatile("s_waitcnt lgkmcnt(8)" ::: "memory")
#define VM6()   asm volatile("s_waitcnt vmcnt(6)" ::: "memory")
#define VM0()   asm volatile("s_waitcnt vmcnt(0)" ::: "memory")

#define LA(BUF, X, MH, KKV) \
  (*(const f16x8*)(lds + (BUF)*16384 + rA + (MH)*4096 + (X)*1024 + (KKV)))
#define LB(BUF, NR, KKV) \
  (*(const f16x8*)(lds + 32768 + (BUF)*16384 + rB + (NR)*1024 + (KKV)))

#define BHALF(BUF, SL, KKV) do { \
    bfr[0][SL]=LB(BUF,0,KKV); bfr[1][SL]=LB(BUF,1,KKV); \
    bfr[2][SL]=LB(BUF,2,KKV); bfr[3][SL]=LB(BUF,3,KKV); \
  } while (0)
#define ALD(T0, T1, T2, T3, BUF, MH, KKV) do { \
    T0 = LA(BUF, 0, MH, KKV); T1 = LA(BUF, 1, MH, KKV); \
    T2 = LA(BUF, 2, MH, KKV); T3 = LA(BUF, 3, MH, KKV); \
  } while (0)

#define MF(A, B, C) __builtin_amdgcn_mfma_f32_16x16x32_f16(A, B, C, 0, 0, 0)
#define MFMAS(A0, A1, A2, A3, MH, KS) do { \
    __builtin_amdgcn_s_setprio(1); \
    acc[(MH)*4+0][0]=MF(A0,bfr[0][KS],acc[(MH)*4+0][0]); \
    acc[(MH)*4+0][1]=MF(A0,bfr[1][KS],acc[(MH)*4+0][1]); \
    acc[(MH)*4+0][2]=MF(A0,bfr[2][KS],acc[(MH)*4+0][2]); \
    acc[(MH)*4+0][3]=MF(A0,bfr[3][KS],acc[(MH)*4+0][3]); \
    acc[(MH)*4+1][0]=MF(A1,bfr[0][KS],acc[(MH)*4+1][0]); \
    acc[(MH)*4+1][1]=MF(A1,bfr[1][KS],acc[(MH)*4+1][1]); \
    acc[(MH)*4+1][2]=MF(A1,bfr[2][KS],acc[(MH)*4+1][2]); \
    acc[(MH)*4+1][3]=MF(A1,bfr[3][KS],acc[(MH)*4+1][3]); \
    acc[(MH)*4+2][0]=MF(A2,bfr[0][KS],acc[(MH)*4+2][0]); \
    acc[(MH)*4+2][1]=MF(A2,bfr[1][KS],acc[(MH)*4+2][1]); \
    acc[(MH)*4+2][2]=MF(A2,bfr[2][KS],acc[(MH)*4+2][2]); \
    acc[(MH)*4+2][3]=MF(A2,bfr[3][KS],acc[(MH)*4+2][3]); \
    acc[(MH)*4+3][0]=MF(A3,bfr[0][KS],acc[(MH)*4+3][0]); \
    acc[(MH)*4+3][1]=MF(A3,bfr[1][KS],acc[(MH)*4+3][1]); \
    acc[(MH)*4+3][2]=MF(A3,bfr[2][KS],acc[(MH)*4+3][2]); \
    acc[(MH)*4+3][3]=MF(A3,bfr[3][KS],acc[(MH)*4+3][3]); \
    __builtin_amdgcn_s_setprio(0); \
  } while (0)

__global__ __launch_bounds__(512, 2) void qkv_gemm_kernel(
    const _Float16* __restrict__ Ah, const _Float16* __restrict__ Wh,
    const float* __restrict__ qb, const float* __restrict__ kb,
    const float* __restrict__ vb, float* __restrict__ out) {
  extern __shared__ _Float16 lds[];   // 131072 B

  const int t    = threadIdx.x;
  const int lane = t & 63;
  const int wid  = t >> 6;            // 0..7
  const int wm   = wid >> 2;          // 0..1 (M)
  const int wn   = wid & 3;           // 0..3 (N)
  const int fr   = lane & 15;
  const int fq   = lane >> 4;

  const int n0  = blockIdx.x * 256;
  const int m0  = blockIdx.y * 256;
  const int p   = n0 >> 11;
  const int ln0 = n0 & (HD - 1);
  const _Float16* Ag  = Ah + (size_t)m0 * HD;
  const _Float16* Bgp = Wh + (size_t)p * HD * HD + (size_t)ln0 * HD;
  const float* bias = (p == 0) ? qb : (p == 1) ? kb : vb;

  // Staging invariants (coalesced + inverse-swizzled source).
  const int srow = t >> 3;                              // 0..63
  const int scol = ((t & 7) ^ (srow & 7)) * 8;          // f16 offset in row
  // Fragment-read invariants.
  const int rA  = (wm * 128 + fr) * 64;
  const int rB  = (wn * 64 + fr) * 64;
  const int kk0 = ((fq) ^ (fr & 7)) * 8;
  const int kk1 = ((4 + fq) ^ (fr & 7)) * 8;

  auto stA = [&](int buf, int hf, int kt) {
    const _Float16* g = Ag + (size_t)(hf * 64 + srow) * HD + kt * 64 + scol;
    _Float16* l = lds + buf * 16384 + (hf * 512 + t) * 8;
    gload16(g, l);
    gload16(g + (size_t)128 * HD, l + 8192);
  };
  auto stB = [&](int buf, int hf, int kt) {
    const _Float16* g = Bgp + (size_t)(hf * 64 + srow) * HD + kt * 64 + scol;
    _Float16* l = lds + 32768 + buf * 16384 + (hf * 512 + t) * 8;
    gload16(g, l);
    gload16(g + (size_t)128 * HD, l + 8192);
  };

  f32x4 acc[8][4] = {};

  // Fragment registers: B rotating set (32 VGPR) + A double sets x/y (16+16).
  f16x8 bfr[4][2];
  f16x8 x0, x1, x2, x3;
  f16x8 y0, y1, y2, y3;

  // Prologue: buf0 <- K-tile 0 (4 halves), buf1 <- K-tile 1 (3 halves).
  // vmcnt(6) = 3 calls in flight -> buf0 fully landed.
  stB(0, 0, 0); stB(0, 1, 0); stA(0, 0, 0); stA(0, 1, 0);
  stB(1, 0, 1); stB(1, 1, 1); stA(1, 0, 1);
  VM6();
  BAR();
  BHALF(0, 0, kk0);
  ALD(x0, x1, x2, x3, 0, 0, kk0);

#pragma unroll 1
  for (int i = 0; i < NIT; ++i) {
    const bool nl = (i < NIT - 1);
    const int kt1 = 2 * i + 1, kt2 = 2 * i + 2, kt3 = 2 * i + 3;

    // ---- P0 ----
    stA(1, 1, kt1);
    BHALF(0, 1, kk1);
    ALD(y0, y1, y2, y3, 0, 0, kk1);
    MFMAS(x0, x1, x2, x3, 0, 0);
    LGKM4(); BAR();

    // ---- P1 ----
    if (nl) stB(0, 0, kt2);
    ALD(x0, x1, x2, x3, 0, 1, kk0);
    MFMAS(y0, y1, y2, y3, 0, 1);
    LGKM4(); BAR();

    // ---- P2 ----
    if (nl) stB(0, 1, kt2);
    ALD(y0, y1, y2, y3, 0, 1, kk1);
    MFMAS(x0, x1, x2, x3, 1, 0);
    LGKM4(); BAR();

    // ---- P3 ----
    if (nl) { stA(0, 0, kt2); VM6(); } else { VM0(); }
    BHALF(1, 0, kk0);
    ALD(x0, x1, x2, x3, 1, 0, kk0);
    MFMAS(y0, y1, y2, y3, 1, 1);
    LGKM8(); BAR();

    // ---- P4 ----
    if (nl) stA(0, 1, kt2);
    BHALF(1, 1, kk1);
    ALD(y0, y1, y2, y3, 1, 0, kk1);
    MFMAS(x0, x1, x2, x3, 0, 0);
    LGKM4(); BAR();

    // ---- P5 ----
    if (nl) stB(1, 0, kt3);
    ALD(x0, x1, x2, x3, 1, 1, kk0);
    MFMAS(y0, y1, y2, y3, 0, 1);
    LGKM4(); BAR();

    // ---- P6 ----
    if (nl) stB(1, 1, kt3);
    ALD(y0, y1, y2, y3, 1, 1, kk1);
    MFMAS(x0, x1, x2, x3, 1, 0);
    LGKM4(); BAR();

    // ---- P7 ----
    if (nl) {
      stA(1, 0, kt3);
      VM6();
      BHALF(0, 0, kk0);
      ALD(x0, x1, x2, x3, 0, 0, kk0);
    }
    MFMAS(y0, y1, y2, y3, 1, 1);
    LGKM8(); BAR();
  }

  // Epilogue: C/D layout col = lane&15, row = (lane>>4)*4 + reg.
  float bv[4];
#pragma unroll
  for (int nr = 0; nr < 4; ++nr)
    bv[nr] = bias[(ln0 + wn * 64 + nr * 16 + fr)];
#pragma unroll
  for (int mr = 0; mr < 8; ++mr) {
    const int r0 = m0 + wm * 128 + mr * 16 + fq * 4;
#pragma unroll
    for (int nr = 0; nr < 4; ++nr) {
      const int cg = n0 + wn * 64 + nr * 16 + fr;
      f32x4 v = acc[mr][nr];
#pragma unroll
      for (int r = 0; r < 4; ++r)
        out[(size_t)(r0 + r) * NTOT + cg] = v[r] + bv[nr];
    }
  }
}

// ---------------------------------------------------------------------------
extern "C" void kernel_launch(void* const* d_in, const int* in_sizes, int n_in,
                              void* d_out, int out_size, void* d_ws,
                              size_t ws_size, hipStream_t stream) {
  const float* x     = (const float*)d_in[0];
  const float* gamma = (const float*)d_in[1];
  const float* beta  = (const float*)d_in[2];
  const float* qw    = (const float*)d_in[3];
  const float* qb    = (const float*)d_in[4];
  const float* kw    = (const float*)d_in[5];
  const float* kbia  = (const float*)d_in[6];
  const float* vw    = (const float*)d_in[7];
  const float* vb    = (const float*)d_in[8];
  float* out = (float*)d_out;

  // Workspace: [0, 32M) normed fp16 [8192][2048]; [32M, 56M) W fp16 [3][2048][2048]
  char* ws = (char*)d_ws;
  _Float16* Ahp = (_Float16*)(ws);
  _Float16* Whp = (_Float16*)(ws + (size_t)MTOT * HD * 2);

  (void)hipFuncSetAttribute((const void*)qkv_gemm_kernel,
                            hipFuncAttributeMaxDynamicSharedMemorySize, 131072);

  prep_kernel<<<MTOT + 3072, 256, 0, stream>>>(x, gamma, beta, qw, kw, vw,
                                               Ahp, Whp);
  qkv_gemm_kernel<<<dim3(NTOT / 256, MTOT / 256), 512, 131072, stream>>>(
      Ahp, Whp, qb, kbia, vb, out);
}